// Round 4
// baseline (505.730 us; speedup 1.0000x reference)
//
#include <hip/hip_runtime.h>

#define NS 65536
#define DD 32
#define RR 128
#define SPB 16            // samples per block
#define STR 132           // padded LDS row stride (floats)

// R8: same per-(rule,sample) arithmetic as R7 (bit-identical outputs), but
// 256-thread blocks: thread = (rule, sample-group). Lanes 0-127 do samples 0-7,
// lanes 128-255 do samples 8-15 of the same 16-sample tile.
// Why: R4/R6/R7 all landed ~46us with VALUBusy 33/59/45% and Occupancy ~22-31%
// (~3.5 blocks = 7 waves/CU). Fitting instruction counts to measured VALU-issue
// time shows the clock sustains ~1.3-1.4GHz on this dispatch, and at 7 waves/CU
// the ds_read latency + exp + prologue stalls go uncovered. LDS (20.5KB) allows
// 7 resident blocks; at 4 waves/block that is 28 waves/CU. Total VALU work is
// unchanged — this round buys busy%, not stream length.
// Diagnostic: if busy% rises to ~80% but dur stays ~40us, the stream is ~2x
// useful work (AGPR copy traffic) and the next move is param-set splitting.
__global__ __launch_bounds__(256, 4) void anfis_main(
    const float* __restrict__ X, const float* __restrict__ A,
    const float* __restrict__ B, const float* __restrict__ C,
    float* __restrict__ out_pred, float* __restrict__ out_str,
    float* __restrict__ out_norm)
{
    __shared__ float SBUF[SPB * STR];   // strengths, row = sample-in-block
    __shared__ float PBUF[SPB * STR];   // strength * rule_out
    __shared__ float XT[SPB * DD];      // block's X tile (512 floats)
    __shared__ float pS[SPB][8];
    __shared__ float pD[SPB][8];
    __shared__ float scale_lds[SPB];

    const int tid   = threadIdx.x;
    const int rule  = tid & 127;        // rule id
    const int j0    = (tid >> 7) * 8;   // sample-group base: 0 or 8
    const int nbase = blockIdx.x * SPB;

    // ---- stage X tile to LDS (coalesced 2KB, 1 float4/thread, first 128) ----
    if (tid < 128)
        ((float4*)XT)[tid] = ((const float4*)(X + (size_t)nbase * DD))[tid];

    // ---- per-thread rule params -> VGPRs (overlap with X staging) ----
    float w_[DD], naw_[DD], ck_[DD], bias;
    {
        const float4* av = (const float4*)(A + rule * DD);
        const float4* bv = (const float4*)(B + rule * DD);
        #pragma unroll
        for (int i = 0; i < 8; ++i) {
            float4 va = av[i], vb = bv[i];
            float w0 = 0.8493218003f * __builtin_amdgcn_rcpf(fmaxf(vb.x, 1e-8f));
            float w1 = 0.8493218003f * __builtin_amdgcn_rcpf(fmaxf(vb.y, 1e-8f));
            float w2 = 0.8493218003f * __builtin_amdgcn_rcpf(fmaxf(vb.z, 1e-8f));
            float w3 = 0.8493218003f * __builtin_amdgcn_rcpf(fmaxf(vb.w, 1e-8f));
            w_[4*i+0] = w0; naw_[4*i+0] = -va.x * w0;
            w_[4*i+1] = w1; naw_[4*i+1] = -va.y * w1;
            w_[4*i+2] = w2; naw_[4*i+2] = -va.z * w2;
            w_[4*i+3] = w3; naw_[4*i+3] = -va.w * w3;
        }
        #pragma unroll
        for (int d = 0; d < DD; ++d) ck_[d] = C[rule * (DD + 1) + d];
        bias = C[rule * (DD + 1) + DD];
    }
    __syncthreads();                    // XT visible to all 4 waves

    // Pin: forbid rematerialization/reload of params inside the sample loop.
    #pragma unroll
    for (int d = 0; d < DD; ++d)
        asm("" : "+v"(w_[d]), "+v"(naw_[d]), "+v"(ck_[d]));
    asm("" : "+v"(bias));

    // load half-sample (16 dims) of sample jj, half hh, into 4 float4s:
    // wave-uniform ds_read_b128 -> same-address broadcast, conflict-free.
    #define LOADH(buf, jj, hh) { _Pragma("unroll") \
        for (int g = 0; g < 4; ++g) \
            buf[g] = *(const float4*)&XT[(jj) * DD + (hh) * 16 + g * 4]; }

    // process 16 dims starting at d0 (same op order as R4/R7 -> bit-identical)
    #define COMPUTEH(buf, d0) { _Pragma("unroll") \
        for (int g = 0; g < 4; ++g) { \
            const int d = (d0) + g * 4; \
            float4 v = buf[g]; \
            float t0 = fmaf(v.x, w_[d+0], naw_[d+0]); s0 = fmaf(t0, t0, s0); r0 = fmaf(v.x, ck_[d+0], r0); \
            float t1 = fmaf(v.y, w_[d+1], naw_[d+1]); s1 = fmaf(t1, t1, s1); r1 = fmaf(v.y, ck_[d+1], r1); \
            float t2 = fmaf(v.z, w_[d+2], naw_[d+2]); s2 = fmaf(t2, t2, s2); r2 = fmaf(v.z, ck_[d+2], r2); \
            float t3 = fmaf(v.w, w_[d+3], naw_[d+3]); s3 = fmaf(t3, t3, s3); r3 = fmaf(v.w, ck_[d+3], r3); \
        } }

    float4 qa[4], qb[4];
    LOADH(qa, j0, 0)
    #pragma unroll 2
    for (int jj = 0; jj < 8; ++jj) {
        const int j = j0 + jj;
        float s0 = 0.f, s1 = 0.f, s2 = 0.f, s3 = 0.f;
        float r0 = bias, r1 = 0.f, r2 = 0.f, r3 = 0.f;
        LOADH(qb, j, 1)                         // issue reads for 2nd half of j
        COMPUTEH(qa, 0)                         // FMA covers the LDS latency
        LOADH(qa, j0 + ((jj + 1) & 7), 0)       // issue reads for 1st half of j+1
        COMPUTEH(qb, 16)
        float st = __builtin_amdgcn_exp2f(-((s0 + s1) + (s2 + s3)));
        float ro = (r0 + r1) + (r2 + r3);
        SBUF[j * STR + rule] = st;
        PBUF[j * STR + rule] = st * ro;
    }
    #undef LOADH
    #undef COMPUTEH
    __syncthreads();

    // ---- per-sample sums over rules: 128 threads = 16 samples x 8 octants
    //      (kept on tid<128 with identical grouping -> bit-identical sums) ----
    if (tid < 128) {
        int s = tid >> 3, o = tid & 7;      // 16B-group o covers 16 floats
        const float4* srow = (const float4*)&SBUF[s * STR + o * 16];
        const float4* prow = (const float4*)&PBUF[s * STR + o * 16];
        float ss = 0.f, dd = 0.f;
        #pragma unroll
        for (int k = 0; k < 4; ++k) {
            float4 v = srow[k]; ss += (v.x + v.y) + (v.z + v.w);
            float4 p = prow[k]; dd += (p.x + p.y) + (p.z + p.w);
        }
        pS[s][o] = ss; pD[s][o] = dd;
    }
    __syncthreads();
    if (tid < SPB) {
        float ss = 0.f, dd = 0.f;
        #pragma unroll
        for (int o = 0; o < 8; ++o) { ss += pS[tid][o]; dd += pD[tid][o]; }
        float sc = 1.0f / (ss + 1e-8f);
        out_pred[nbase + tid] = dd * sc;
        scale_lds[tid] = sc;
    }
    __syncthreads();

    // ---- flush strengths + normalized, float4-coalesced, all 256 threads ----
    #pragma unroll
    for (int it = 0; it < 2; ++it) {
        int f   = it * 256 + tid;       // float4 index over 16x32 tile
        int row = f >> 5;
        int col = f & 31;
        float4 v = *(const float4*)&SBUF[row * STR + col * 4];
        float sc = scale_lds[row];
        size_t base = ((size_t)(nbase + row)) * RR + col * 4;
        *(float4*)(out_str  + base) = v;
        *(float4*)(out_norm + base) = make_float4(v.x * sc, v.y * sc, v.z * sc, v.w * sc);
    }
}

extern "C" void kernel_launch(void* const* d_in, const int* in_sizes, int n_in,
                              void* d_out, int out_size, void* d_ws, size_t ws_size,
                              hipStream_t stream) {
    const float* X = (const float*)d_in[0];
    const float* A = (const float*)d_in[1];
    const float* B = (const float*)d_in[2];
    const float* C = (const float*)d_in[3];

    float* pred = (float*)d_out;
    float* str  = pred + NS;
    float* nrm  = str + (size_t)NS * RR;

    anfis_main<<<dim3(NS / SPB), dim3(256), 0, stream>>>(X, A, B, C, pred, str, nrm);
}

// Round 5
// 122.744 us; speedup vs baseline: 4.1202x; 4.1202x over previous
//
#include <hip/hip_runtime.h>

#define NS 65536
#define DD 32
#define RR 128
#define SPB 16            // samples per block
#define STR 132           // padded LDS row stride (floats)

// R9 = R8 structure (256-thread / 4-wave blocks, thread = (rule, sample-group))
// with R7's register budget restored: __launch_bounds__(256, 3).
// R8's catastrophic regression (448us) was pure scratch spill: budget 128 regs
// (256,4) vs ~145 demand -> FETCH 4.3MB->1.1GB, WRITE 66->578MB, VALU 5.6%.
// R7 worked only because (128,3) gave ~170 regs. R8 nevertheless CONFIRMED the
// occupancy theory: 45% occupancy vs R7's 22%. R9 keeps the 4-wave blocks
// (12 waves/CU at 3 blocks -> 3 waves/SIMD cover the ds_read latency that
// R7's ~1.7 waves/SIMD exposed) and the 170-reg budget (no spill).
// Arithmetic identical to R4/R7/R8 => bit-identical outputs.
__global__ __launch_bounds__(256, 3) void anfis_main(
    const float* __restrict__ X, const float* __restrict__ A,
    const float* __restrict__ B, const float* __restrict__ C,
    float* __restrict__ out_pred, float* __restrict__ out_str,
    float* __restrict__ out_norm)
{
    __shared__ float SBUF[SPB * STR];   // strengths, row = sample-in-block
    __shared__ float PBUF[SPB * STR];   // strength * rule_out
    __shared__ float XT[SPB * DD];      // block's X tile (512 floats)
    __shared__ float pS[SPB][8];
    __shared__ float pD[SPB][8];
    __shared__ float scale_lds[SPB];

    const int tid   = threadIdx.x;
    const int rule  = tid & 127;        // rule id
    const int j0    = (tid >> 7) * 8;   // sample-group base: 0 or 8
    const int nbase = blockIdx.x * SPB;

    // ---- stage X tile to LDS (coalesced 2KB, 1 float4/thread, first 128) ----
    if (tid < 128)
        ((float4*)XT)[tid] = ((const float4*)(X + (size_t)nbase * DD))[tid];

    // ---- per-thread rule params -> VGPRs (overlap with X staging) ----
    float w_[DD], naw_[DD], ck_[DD], bias;
    {
        const float4* av = (const float4*)(A + rule * DD);
        const float4* bv = (const float4*)(B + rule * DD);
        #pragma unroll
        for (int i = 0; i < 8; ++i) {
            float4 va = av[i], vb = bv[i];
            float w0 = 0.8493218003f * __builtin_amdgcn_rcpf(fmaxf(vb.x, 1e-8f));
            float w1 = 0.8493218003f * __builtin_amdgcn_rcpf(fmaxf(vb.y, 1e-8f));
            float w2 = 0.8493218003f * __builtin_amdgcn_rcpf(fmaxf(vb.z, 1e-8f));
            float w3 = 0.8493218003f * __builtin_amdgcn_rcpf(fmaxf(vb.w, 1e-8f));
            w_[4*i+0] = w0; naw_[4*i+0] = -va.x * w0;
            w_[4*i+1] = w1; naw_[4*i+1] = -va.y * w1;
            w_[4*i+2] = w2; naw_[4*i+2] = -va.z * w2;
            w_[4*i+3] = w3; naw_[4*i+3] = -va.w * w3;
        }
        #pragma unroll
        for (int d = 0; d < DD; ++d) ck_[d] = C[rule * (DD + 1) + d];
        bias = C[rule * (DD + 1) + DD];
    }
    __syncthreads();                    // XT visible to all 4 waves

    // Pin: forbid rematerialization/reload of params inside the sample loop.
    #pragma unroll
    for (int d = 0; d < DD; ++d)
        asm("" : "+v"(w_[d]), "+v"(naw_[d]), "+v"(ck_[d]));
    asm("" : "+v"(bias));

    // load half-sample (16 dims) of sample jj, half hh, into 4 float4s:
    // wave-uniform ds_read_b128 -> same-address broadcast, conflict-free.
    #define LOADH(buf, jj, hh) { _Pragma("unroll") \
        for (int g = 0; g < 4; ++g) \
            buf[g] = *(const float4*)&XT[(jj) * DD + (hh) * 16 + g * 4]; }

    // process 16 dims starting at d0 (same op order as R4/R7 -> bit-identical)
    #define COMPUTEH(buf, d0) { _Pragma("unroll") \
        for (int g = 0; g < 4; ++g) { \
            const int d = (d0) + g * 4; \
            float4 v = buf[g]; \
            float t0 = fmaf(v.x, w_[d+0], naw_[d+0]); s0 = fmaf(t0, t0, s0); r0 = fmaf(v.x, ck_[d+0], r0); \
            float t1 = fmaf(v.y, w_[d+1], naw_[d+1]); s1 = fmaf(t1, t1, s1); r1 = fmaf(v.y, ck_[d+1], r1); \
            float t2 = fmaf(v.z, w_[d+2], naw_[d+2]); s2 = fmaf(t2, t2, s2); r2 = fmaf(v.z, ck_[d+2], r2); \
            float t3 = fmaf(v.w, w_[d+3], naw_[d+3]); s3 = fmaf(t3, t3, s3); r3 = fmaf(v.w, ck_[d+3], r3); \
        } }

    float4 qa[4], qb[4];
    LOADH(qa, j0, 0)
    #pragma unroll 2
    for (int jj = 0; jj < 8; ++jj) {
        const int j = j0 + jj;
        float s0 = 0.f, s1 = 0.f, s2 = 0.f, s3 = 0.f;
        float r0 = bias, r1 = 0.f, r2 = 0.f, r3 = 0.f;
        LOADH(qb, j, 1)                         // issue reads for 2nd half of j
        COMPUTEH(qa, 0)                         // FMA covers the LDS latency
        LOADH(qa, j0 + ((jj + 1) & 7), 0)       // issue reads for 1st half of j+1
        COMPUTEH(qb, 16)
        float st = __builtin_amdgcn_exp2f(-((s0 + s1) + (s2 + s3)));
        float ro = (r0 + r1) + (r2 + r3);
        SBUF[j * STR + rule] = st;
        PBUF[j * STR + rule] = st * ro;
    }
    #undef LOADH
    #undef COMPUTEH
    __syncthreads();

    // ---- per-sample sums over rules: 128 threads = 16 samples x 8 octants
    //      (kept on tid<128 with identical grouping -> bit-identical sums) ----
    if (tid < 128) {
        int s = tid >> 3, o = tid & 7;      // 16B-group o covers 16 floats
        const float4* srow = (const float4*)&SBUF[s * STR + o * 16];
        const float4* prow = (const float4*)&PBUF[s * STR + o * 16];
        float ss = 0.f, dd = 0.f;
        #pragma unroll
        for (int k = 0; k < 4; ++k) {
            float4 v = srow[k]; ss += (v.x + v.y) + (v.z + v.w);
            float4 p = prow[k]; dd += (p.x + p.y) + (p.z + p.w);
        }
        pS[s][o] = ss; pD[s][o] = dd;
    }
    __syncthreads();
    if (tid < SPB) {
        float ss = 0.f, dd = 0.f;
        #pragma unroll
        for (int o = 0; o < 8; ++o) { ss += pS[tid][o]; dd += pD[tid][o]; }
        float sc = 1.0f / (ss + 1e-8f);
        out_pred[nbase + tid] = dd * sc;
        scale_lds[tid] = sc;
    }
    __syncthreads();

    // ---- flush strengths + normalized, float4-coalesced, all 256 threads ----
    #pragma unroll
    for (int it = 0; it < 2; ++it) {
        int f   = it * 256 + tid;       // float4 index over 16x32 tile
        int row = f >> 5;
        int col = f & 31;
        float4 v = *(const float4*)&SBUF[row * STR + col * 4];
        float sc = scale_lds[row];
        size_t base = ((size_t)(nbase + row)) * RR + col * 4;
        *(float4*)(out_str  + base) = v;
        *(float4*)(out_norm + base) = make_float4(v.x * sc, v.y * sc, v.z * sc, v.w * sc);
    }
}

extern "C" void kernel_launch(void* const* d_in, const int* in_sizes, int n_in,
                              void* d_out, int out_size, void* d_ws, size_t ws_size,
                              hipStream_t stream) {
    const float* X = (const float*)d_in[0];
    const float* A = (const float*)d_in[1];
    const float* B = (const float*)d_in[2];
    const float* C = (const float*)d_in[3];

    float* pred = (float*)d_out;
    float* str  = pred + NS;
    float* nrm  = str + (size_t)NS * RR;

    anfis_main<<<dim3(NS / SPB), dim3(256), 0, stream>>>(X, A, B, C, pred, str, nrm);
}

// Round 6
// 109.104 us; speedup vs baseline: 4.6353x; 1.1250x over previous
//
#include <hip/hip_runtime.h>

#define NS 65536
#define DD 32
#define RR 128
#define SPB 16            // samples per block-tile
#define STR 132           // padded LDS row stride (floats)
#define NBLK 2048         // persistent blocks; each does tiles {b, b+NBLK}

// R10 = R7's exact shape (128 thr / 2 waves, (128,3) budget, thread=rule,
// SPB=16, identical arithmetic) made 2-tile persistent.
// Evidence: R9 showed 4-wave blocks lose by REPLICATING the prologue (every
// thread loads+preprocesses 97 params; 2x wave-prologues for the same 16
// samples => 46->62us). R7's residual gap to the ~16us issue floor is ~30%
// prologue overhead (16 block-slots/CU, each a serialized param-load+pin
// fence + cold X read) + idle from churning short blocks.
// R10: (1) params loaded+pinned ONCE per block, serving 2 tiles (prologues/SIMD
// 8->4); (2) tile-1's X prefetched into regs BEFORE tile-0's j-loop and
// ds_written to LDS after tile-0's flush (T14 issue-early/write-late: ~3000cy
// of cover) -> tile 1 starts with zero cold-X latency; (3) grid 2048: 8 blocks
// queued/CU, 6 resident (VGPR-limited) -> steadier ~12 waves/CU.
// Per-(sample,rule) op order untouched => bit-identical outputs.
__global__ __launch_bounds__(128, 3) void anfis_main(
    const float* __restrict__ X, const float* __restrict__ A,
    const float* __restrict__ B, const float* __restrict__ C,
    float* __restrict__ out_pred, float* __restrict__ out_str,
    float* __restrict__ out_norm)
{
    __shared__ float SBUF[SPB * STR];   // strengths, row = sample-in-tile
    __shared__ float PBUF[SPB * STR];   // strength * rule_out
    __shared__ float XT[2][SPB * DD];   // X tiles (2KB each)
    __shared__ float pS[SPB][8];
    __shared__ float pD[SPB][8];
    __shared__ float scale_lds[SPB];

    const int tid = threadIdx.x;        // rule id
    const int t0  = blockIdx.x;
    const int t1  = blockIdx.x + NBLK;

    // ---- stage tile-0 X to LDS (coalesced 2KB, 1 float4/thread) ----
    ((float4*)XT[0])[tid] = ((const float4*)(X + (size_t)t0 * SPB * DD))[tid];

    // ---- per-thread rule params -> VGPRs (once per block) ----
    float w_[DD], naw_[DD], ck_[DD], bias;
    {
        const float4* av = (const float4*)(A + tid * DD);
        const float4* bv = (const float4*)(B + tid * DD);
        #pragma unroll
        for (int i = 0; i < 8; ++i) {
            float4 va = av[i], vb = bv[i];
            float w0 = 0.8493218003f * __builtin_amdgcn_rcpf(fmaxf(vb.x, 1e-8f));
            float w1 = 0.8493218003f * __builtin_amdgcn_rcpf(fmaxf(vb.y, 1e-8f));
            float w2 = 0.8493218003f * __builtin_amdgcn_rcpf(fmaxf(vb.z, 1e-8f));
            float w3 = 0.8493218003f * __builtin_amdgcn_rcpf(fmaxf(vb.w, 1e-8f));
            w_[4*i+0] = w0; naw_[4*i+0] = -va.x * w0;
            w_[4*i+1] = w1; naw_[4*i+1] = -va.y * w1;
            w_[4*i+2] = w2; naw_[4*i+2] = -va.z * w2;
            w_[4*i+3] = w3; naw_[4*i+3] = -va.w * w3;
        }
        #pragma unroll
        for (int d = 0; d < DD; ++d) ck_[d] = C[tid * (DD + 1) + d];
        bias = C[tid * (DD + 1) + DD];
    }
    __syncthreads();                    // XT[0] visible to both waves

    // Pin once: forbid rematerialization/reload inside the tile/sample loops.
    #pragma unroll
    for (int d = 0; d < DD; ++d)
        asm("" : "+v"(w_[d]), "+v"(naw_[d]), "+v"(ck_[d]));
    asm("" : "+v"(bias));

    // ---- prefetch tile-1 X into regs; written to LDS after tile-0's flush ----
    float4 px = ((const float4*)(X + (size_t)t1 * SPB * DD))[tid];

    #define LOADH(xt, buf, jj, hh) { _Pragma("unroll") \
        for (int g = 0; g < 4; ++g) \
            buf[g] = *(const float4*)&(xt)[(jj) * DD + (hh) * 16 + g * 4]; }

    #define COMPUTEH(buf, d0) { _Pragma("unroll") \
        for (int g = 0; g < 4; ++g) { \
            const int d = (d0) + g * 4; \
            float4 v = buf[g]; \
            float t0_ = fmaf(v.x, w_[d+0], naw_[d+0]); s0 = fmaf(t0_, t0_, s0); r0 = fmaf(v.x, ck_[d+0], r0); \
            float t1_ = fmaf(v.y, w_[d+1], naw_[d+1]); s1 = fmaf(t1_, t1_, s1); r1 = fmaf(v.y, ck_[d+1], r1); \
            float t2_ = fmaf(v.z, w_[d+2], naw_[d+2]); s2 = fmaf(t2_, t2_, s2); r2 = fmaf(v.z, ck_[d+2], r2); \
            float t3_ = fmaf(v.w, w_[d+3], naw_[d+3]); s3 = fmaf(t3_, t3_, s3); r3 = fmaf(v.w, ck_[d+3], r3); \
        } }

    for (int tt = 0; tt < 2; ++tt) {
        const int   nbase = (tt ? t1 : t0) * SPB;
        const float* xt   = XT[tt];

        // ---- main loop: 16 samples, half-sample LDS double-buffer ----
        float4 qa[4], qb[4];
        LOADH(xt, qa, 0, 0)
        #pragma unroll 2
        for (int j = 0; j < SPB; ++j) {
            float s0 = 0.f, s1 = 0.f, s2 = 0.f, s3 = 0.f;
            float r0 = bias, r1 = 0.f, r2 = 0.f, r3 = 0.f;
            LOADH(xt, qb, j, 1)                     // reads for 2nd half of j
            COMPUTEH(qa, 0)                         // FMA covers LDS latency
            LOADH(xt, qa, (j + 1) & (SPB - 1), 0)   // reads for 1st half of j+1
            COMPUTEH(qb, 16)
            float st = __builtin_amdgcn_exp2f(-((s0 + s1) + (s2 + s3)));
            float ro = (r0 + r1) + (r2 + r3);
            SBUF[j * STR + tid] = st;
            PBUF[j * STR + tid] = st * ro;
        }
        __syncthreads();

        // ---- per-sample sums: 128 threads = 16 samples x 8 octants ----
        {
            int s = tid >> 3, o = tid & 7;
            const float4* srow = (const float4*)&SBUF[s * STR + o * 16];
            const float4* prow = (const float4*)&PBUF[s * STR + o * 16];
            float ss = 0.f, dd = 0.f;
            #pragma unroll
            for (int k = 0; k < 4; ++k) {
                float4 v = srow[k]; ss += (v.x + v.y) + (v.z + v.w);
                float4 p = prow[k]; dd += (p.x + p.y) + (p.z + p.w);
            }
            pS[s][o] = ss; pD[s][o] = dd;
        }
        __syncthreads();
        if (tid < SPB) {
            float ss = 0.f, dd = 0.f;
            #pragma unroll
            for (int o = 0; o < 8; ++o) { ss += pS[tid][o]; dd += pD[tid][o]; }
            float sc = 1.0f / (ss + 1e-8f);
            out_pred[nbase + tid] = dd * sc;
            scale_lds[tid] = sc;
        }
        __syncthreads();

        // ---- flush strengths + normalized, float4-coalesced ----
        #pragma unroll
        for (int it = 0; it < 4; ++it) {
            int f   = it * 128 + tid;
            int row = f >> 5;
            int col = f & 31;
            float4 v = *(const float4*)&SBUF[row * STR + col * 4];
            float sc = scale_lds[row];
            size_t base = ((size_t)(nbase + row)) * RR + col * 4;
            *(float4*)(out_str  + base) = v;
            *(float4*)(out_norm + base) = make_float4(v.x * sc, v.y * sc, v.z * sc, v.w * sc);
        }

        if (tt == 0) {
            // write-late half of the tile-1 X prefetch (px vmcnt-waited here);
            // barrier also orders tile-0 flush (SBUF reads) before tile-1's
            // SBUF writes.
            ((float4*)XT[1])[tid] = px;
            __syncthreads();
        }
    }
    #undef LOADH
    #undef COMPUTEH
}

extern "C" void kernel_launch(void* const* d_in, const int* in_sizes, int n_in,
                              void* d_out, int out_size, void* d_ws, size_t ws_size,
                              hipStream_t stream) {
    const float* X = (const float*)d_in[0];
    const float* A = (const float*)d_in[1];
    const float* B = (const float*)d_in[2];
    const float* C = (const float*)d_in[3];

    float* pred = (float*)d_out;
    float* str  = pred + NS;
    float* nrm  = str + (size_t)NS * RR;

    anfis_main<<<dim3(NBLK), dim3(128), 0, stream>>>(X, A, B, C, pred, str, nrm);
}

// Round 7
// 105.173 us; speedup vs baseline: 4.8085x; 1.0374x over previous
//
#include <hip/hip_runtime.h>

#define NS 65536
#define DD 32
#define RR 128
#define SPB 16            // samples per block
#define STR 132           // padded LDS row stride (floats)

typedef float f2 __attribute__((ext_vector_type(2)));

// One packed f32 FMA: d = a*b + c elementwise on a 2-float VGPR pair.
// Exact per-element FMA -> same rounding as scalar fmaf in the same slot order.
static __device__ __forceinline__ f2 pkfma(f2 a, f2 b, f2 c) {
    f2 d;
    asm("v_pk_fma_f32 %0, %1, %2, %3" : "=v"(d) : "v"(a), "v"(b), "v"(c));
    return d;
}

// R11 = R7 skeleton + v_pk_fma_f32 main loop + pred-store moved past the barrier.
// Consolidated model (R4/R6/R7/R10): VALU-busy time fits instruction counts only
// at ~1.0-1.3GHz effective clock (45us bursts never ramp DVFS). So dur ~= issue
// (~20us, ~45%) + stalls (~25us). pk_fma halves the dominant FMA issue: dims
// (d,d+1)->slots(s0,s1), (d+2,d+3)->(s2,s3); per-slot accumulation sequences and
// the final sum tree are unchanged => bit-identical outputs. hipcc never emits
// v_pk_fma_f32 from scalar code (157.3TF fp32 spec = 2x scalar rate requires it),
// hence inline asm. Also: out_pred store was BEFORE a __syncthreads -> its
// mandatory vmcnt(0) drain stalled the block on one HBM store per tile; moved
// after the barrier (flush + pred now drain only at kernel end).
__global__ __launch_bounds__(128, 3) void anfis_main(
    const float* __restrict__ X, const float* __restrict__ A,
    const float* __restrict__ B, const float* __restrict__ C,
    float* __restrict__ out_pred, float* __restrict__ out_str,
    float* __restrict__ out_norm)
{
    __shared__ float SBUF[SPB * STR];   // strengths, row = sample-in-block
    __shared__ float PBUF[SPB * STR];   // strength * rule_out
    __shared__ float XT[SPB * DD];      // block's X tile (512 floats)
    __shared__ float pS[SPB][8];
    __shared__ float pD[SPB][8];
    __shared__ float scale_lds[SPB];

    const int tid   = threadIdx.x;      // rule id
    const int nbase = blockIdx.x * SPB;

    // ---- stage X tile to LDS (coalesced 2KB, 1 float4/thread) ----
    ((float4*)XT)[tid] = ((const float4*)(X + (size_t)nbase * DD))[tid];

    // ---- per-thread rule params -> VGPR pairs (f2), loaded once ----
    // group i covers dims 4i..4i+3: *01 holds (4i,4i+1), *23 holds (4i+2,4i+3)
    f2 w01_[8], w23_[8], n01_[8], n23_[8], c01_[8], c23_[8];
    float bias;
    {
        const float4* av = (const float4*)(A + tid * DD);
        const float4* bv = (const float4*)(B + tid * DD);
        #pragma unroll
        for (int i = 0; i < 8; ++i) {
            float4 va = av[i], vb = bv[i];
            float w0 = 0.8493218003f * __builtin_amdgcn_rcpf(fmaxf(vb.x, 1e-8f));
            float w1 = 0.8493218003f * __builtin_amdgcn_rcpf(fmaxf(vb.y, 1e-8f));
            float w2 = 0.8493218003f * __builtin_amdgcn_rcpf(fmaxf(vb.z, 1e-8f));
            float w3 = 0.8493218003f * __builtin_amdgcn_rcpf(fmaxf(vb.w, 1e-8f));
            w01_[i] = f2{w0, w1};            w23_[i] = f2{w2, w3};
            n01_[i] = f2{-va.x * w0, -va.y * w1};
            n23_[i] = f2{-va.z * w2, -va.w * w3};
            c01_[i] = f2{C[tid * (DD + 1) + 4*i + 0], C[tid * (DD + 1) + 4*i + 1]};
            c23_[i] = f2{C[tid * (DD + 1) + 4*i + 2], C[tid * (DD + 1) + 4*i + 3]};
        }
        bias = C[tid * (DD + 1) + DD];
    }
    __syncthreads();                    // XT visible to both waves

    // Pin: forbid rematerialization/reload of params inside the sample loop.
    #pragma unroll
    for (int i = 0; i < 8; ++i)
        asm("" : "+v"(w01_[i]), "+v"(w23_[i]), "+v"(n01_[i]),
                 "+v"(n23_[i]), "+v"(c01_[i]), "+v"(c23_[i]));
    asm("" : "+v"(bias));

    // load half-sample (16 dims) of sample jj, half hh, into 4 float4s:
    // wave-uniform ds_read_b128 -> same-address broadcast, conflict-free.
    #define LOADH(buf, jj, hh) { _Pragma("unroll") \
        for (int g = 0; g < 4; ++g) \
            buf[g] = *(const float4*)&XT[(jj) * DD + (hh) * 16 + g * 4]; }

    // process 4 groups (16 dims) starting at group gbase; packed slots keep the
    // exact per-slot op sequence of the scalar version (s0..s3 <-> s01,s23).
    #define COMPUTEH(buf, gbase) { _Pragma("unroll") \
        for (int g = 0; g < 4; ++g) { \
            const int gi = (gbase) + g; \
            const f2* xp2 = (const f2*)&buf[g]; \
            f2 x01 = xp2[0], x23 = xp2[1]; \
            f2 t01 = pkfma(x01, w01_[gi], n01_[gi]); \
            s01 = pkfma(t01, t01, s01); \
            r01 = pkfma(x01, c01_[gi], r01); \
            f2 t23 = pkfma(x23, w23_[gi], n23_[gi]); \
            s23 = pkfma(t23, t23, s23); \
            r23 = pkfma(x23, c23_[gi], r23); \
        } }

    float4 qa[4], qb[4];
    LOADH(qa, 0, 0)
    #pragma unroll 2
    for (int j = 0; j < SPB; ++j) {
        f2 s01 = f2{0.f, 0.f}, s23 = f2{0.f, 0.f};
        f2 r01 = f2{bias, 0.f}, r23 = f2{0.f, 0.f};
        LOADH(qb, j, 1)                     // issue reads for 2nd half of j
        COMPUTEH(qa, 0)                     // pk-FMAs cover the LDS latency
        LOADH(qa, (j + 1) & (SPB - 1), 0)   // issue reads for 1st half of j+1
        COMPUTEH(qb, 4)
        float st = __builtin_amdgcn_exp2f(-((s01.x + s01.y) + (s23.x + s23.y)));
        float ro = (r01.x + r01.y) + (r23.x + r23.y);
        SBUF[j * STR + tid] = st;
        PBUF[j * STR + tid] = st * ro;
    }
    #undef LOADH
    #undef COMPUTEH
    __syncthreads();

    // ---- per-sample sums over rules: 128 threads = 16 samples x 8 octants ----
    {
        int s = tid >> 3, o = tid & 7;      // 16B-group o covers 16 floats
        const float4* srow = (const float4*)&SBUF[s * STR + o * 16];
        const float4* prow = (const float4*)&PBUF[s * STR + o * 16];
        float ss = 0.f, dd = 0.f;
        #pragma unroll
        for (int k = 0; k < 4; ++k) {
            float4 v = srow[k]; ss += (v.x + v.y) + (v.z + v.w);
            float4 p = prow[k]; dd += (p.x + p.y) + (p.z + p.w);
        }
        pS[s][o] = ss; pD[s][o] = dd;
    }
    __syncthreads();
    float predv = 0.f;
    if (tid < SPB) {
        float ss = 0.f, dd = 0.f;
        #pragma unroll
        for (int o = 0; o < 8; ++o) { ss += pS[tid][o]; dd += pD[tid][o]; }
        float sc = 1.0f / (ss + 1e-8f);
        predv = dd * sc;                // store deferred past the barrier:
        scale_lds[tid] = sc;            // no global-store vmcnt drain at the sync
    }
    __syncthreads();
    if (tid < SPB) out_pred[nbase + tid] = predv;

    // ---- flush strengths + normalized, float4-coalesced ----
    #pragma unroll
    for (int it = 0; it < 4; ++it) {
        int f   = it * 128 + tid;       // float4 index over 16x32 tile
        int row = f >> 5;
        int col = f & 31;
        float4 v = *(const float4*)&SBUF[row * STR + col * 4];
        float sc = scale_lds[row];
        size_t base = ((size_t)(nbase + row)) * RR + col * 4;
        *(float4*)(out_str  + base) = v;
        *(float4*)(out_norm + base) = make_float4(v.x * sc, v.y * sc, v.z * sc, v.w * sc);
    }
}

extern "C" void kernel_launch(void* const* d_in, const int* in_sizes, int n_in,
                              void* d_out, int out_size, void* d_ws, size_t ws_size,
                              hipStream_t stream) {
    const float* X = (const float*)d_in[0];
    const float* A = (const float*)d_in[1];
    const float* B = (const float*)d_in[2];
    const float* C = (const float*)d_in[3];

    float* pred = (float*)d_out;
    float* str  = pred + NS;
    float* nrm  = str + (size_t)NS * RR;

    anfis_main<<<dim3(NS / SPB), dim3(128), 0, stream>>>(X, A, B, C, pred, str, nrm);
}